// Round 8
// baseline (188.740 us; speedup 1.0000x reference)
//
#include <hip/hip_runtime.h>

typedef float f32x4 __attribute__((ext_vector_type(4)));
typedef float f32x16 __attribute__((ext_vector_type(16)));
typedef short bf16x8 __attribute__((ext_vector_type(8)));
typedef unsigned int uint;
typedef unsigned short ushort_t;

#define EMB    512
#define NSEQ   2048
#define NBATCH 4
#define NHEAD  8
#define MROWS  (NBATCH * NSEQ)   // 8192
#define CEXP   0.06375872f       // log2(e) / sqrt(512)

// round-to-nearest-even fp32 -> bf16 (bit trick)
__device__ __forceinline__ uint f2bf(float x) {
    uint u = __builtin_bit_cast(uint, x);
    return (u + 0x7fffu + ((u >> 16) & 1u)) >> 16;
}

// async global->LDS, 16B per lane; LDS dest = wave-uniform base + lane*16
__device__ __forceinline__ void glds16(const void* g, void* l) {
    __builtin_amdgcn_global_load_lds(
        (const __attribute__((address_space(1))) uint*)g,
        (__attribute__((address_space(3))) uint*)l, 16, 0, 0);
}

// ---------------------------------------------------------------------------
// Prep (weights only now): Wq|Wk|Wv -> Wqkvb bf16 [1536][512]; bias concat;
// Wo -> bf16.  x conversion is folded into gemm128<0> A-staging.
// ---------------------------------------------------------------------------
__global__ __launch_bounds__(256)
void prep(const float* __restrict__ Wq, const float* __restrict__ Wk,
          const float* __restrict__ Wv, const float* __restrict__ Wo,
          const float* __restrict__ bq, const float* __restrict__ bk,
          const float* __restrict__ bv,
          ushort_t* __restrict__ Wqkvb, float* __restrict__ bqkv,
          ushort_t* __restrict__ Wob) {
    int t = blockIdx.x * 256 + threadIdx.x;   // 0..65535 (512*512/4 groups)
    {
        float4 a = ((const float4*)Wq)[t];
        float4 b = ((const float4*)Wk)[t];
        float4 c = ((const float4*)Wv)[t];
        float4 d = ((const float4*)Wo)[t];
        uint2 p;
        p.x = f2bf(a.x) | (f2bf(a.y) << 16); p.y = f2bf(a.z) | (f2bf(a.w) << 16);
        ((uint2*)Wqkvb)[t] = p;
        p.x = f2bf(b.x) | (f2bf(b.y) << 16); p.y = f2bf(b.z) | (f2bf(b.w) << 16);
        ((uint2*)Wqkvb)[t + 65536] = p;
        p.x = f2bf(c.x) | (f2bf(c.y) << 16); p.y = f2bf(c.z) | (f2bf(c.w) << 16);
        ((uint2*)Wqkvb)[t + 131072] = p;
        p.x = f2bf(d.x) | (f2bf(d.y) << 16); p.y = f2bf(d.z) | (f2bf(d.w) << 16);
        ((uint2*)Wob)[t] = p;
    }
    if (t < 512) {
        bqkv[t] = bq[t]; bqkv[512 + t] = bk[t]; bqkv[1024 + t] = bv[t];
    }
}

// ---------------------------------------------------------------------------
// GEMM C[8192 x N] = A[8192x512] * BT[Nx512]bf16 + bias, 128x128 tile,
// BK=32, 4 waves, 16x16x32 mfma, 4x4 subtiles/wave.
// MODE 0: A = x in fp32, register-staged with inline truncation to bf16
//         (kills the prep x pass). B via glds16. N=1536 QKV epilogues.
// MODE 1: A = AOb bf16 via glds16 (m97 pattern). out proj fp32 epilogue.
// ---------------------------------------------------------------------------
template<int MODE>
__global__ __launch_bounds__(256)
void gemm128(const float* __restrict__ Af, const ushort_t* __restrict__ A,
             const ushort_t* __restrict__ BT,
             const float* __restrict__ bias, ushort_t* __restrict__ oQK,
             ushort_t* __restrict__ oVT, float* __restrict__ oC) {
    __shared__ ushort_t As[128][32];   // 8 KB, unpadded
    __shared__ ushort_t Bs[128][32];
    __shared__ float ep[32][132];      // epilogue transpose buffer (16.9 KB)
    const int tid = threadIdx.x, wave = tid >> 6, lane = tid & 63;
    const int m0 = blockIdx.x * 128, n0 = blockIdx.y * 128;
    const int wr = (wave & 1) * 64, wc = (wave >> 1) * 64;

    f32x4 acc[4][4];
#pragma unroll
    for (int i = 0; i < 4; ++i)
#pragma unroll
        for (int j = 0; j < 4; ++j) acc[i][j] = (f32x4){0.f, 0.f, 0.f, 0.f};

    // glds16 lane mapping (B always; A only in MODE 1)
    const int grow = wave * 16 + (lane >> 2);
    const int gcol = (lane & 3) * 8;
    const ushort_t* Ag = (MODE == 1) ? A + (size_t)(m0 + grow) * 512 + gcol : nullptr;
    const ushort_t* Bg = BT + (size_t)(n0 + grow) * 512 + gcol;
    ushort_t* lA0 = &As[wave * 16][0];
    ushort_t* lA1 = &As[64 + wave * 16][0];
    ushort_t* lB0 = &Bs[wave * 16][0];
    ushort_t* lB1 = &Bs[64 + wave * 16][0];
    // fp32 A staging mapping (MODE 0): thread covers 16 floats of one row
    const int asr = tid >> 1, ash = (tid & 1) * 16;
    const float* Axg = (MODE == 0) ? Af + (size_t)(m0 + asr) * 512 + ash : nullptr;
    const int fr = lane & 15, fc = (lane >> 4) * 8;

    for (int kt = 0; kt < 16; ++kt) {
        uint4 f[4];
        if (MODE == 0) {
#pragma unroll
            for (int i = 0; i < 4; ++i)
                f[i] = *(const uint4*)(Axg + kt * 32 + 4 * i);
        }
        __syncthreads();   // prior frag reads done before overwrite
        if (MODE == 0) {
            uint pk[8];
#pragma unroll
            for (int i = 0; i < 8; ++i) {
                uint u0 = ((const uint*)&f[i >> 1])[(i & 1) * 2];
                uint u1 = ((const uint*)&f[i >> 1])[(i & 1) * 2 + 1];
                pk[i] = (u0 >> 16) | (u1 & 0xffff0000u);   // truncate-pack
            }
            *(uint4*)&As[asr][ash]     = *(const uint4*)&pk[0];
            *(uint4*)&As[asr][ash + 8] = *(const uint4*)&pk[4];
        } else {
            glds16(Ag + kt * 32,            lA0);
            glds16(Ag + kt * 32 + 64 * 512, lA1);
        }
        glds16(Bg + kt * 32,            lB0);
        glds16(Bg + kt * 32 + 64 * 512, lB1);
        __syncthreads();   // drains vmcnt+lgkm -> tiles visible
        bf16x8 af[4], bf[4];
#pragma unroll
        for (int i = 0; i < 4; ++i) af[i] = *(const bf16x8*)&As[wr + i * 16 + fr][fc];
#pragma unroll
        for (int j = 0; j < 4; ++j) bf[j] = *(const bf16x8*)&Bs[wc + j * 16 + fr][fc];
#pragma unroll
        for (int i = 0; i < 4; ++i)
#pragma unroll
            for (int j = 0; j < 4; ++j)
                acc[i][j] = __builtin_amdgcn_mfma_f32_16x16x32_bf16(af[i], bf[j], acc[i][j], 0, 0, 0);
    }

    const int col_l = lane & 15, row_l = (lane >> 4) * 4;

    if (MODE == 0 && n0 >= 1024) {
        // V part: direct transposed packed stores
#pragma unroll
        for (int j = 0; j < 4; ++j) {
            const int col = n0 + wc + j * 16 + col_l;
            const float bv = bias[col];
#pragma unroll
            for (int i = 0; i < 4; ++i) {
                const int row = m0 + wr + i * 16 + row_l;
                f32x4 v = acc[i][j];
                v += (f32x4){bv, bv, bv, bv};
                const int e = col - 1024;
                const int b = row >> 11, tok = row & 2047;
                uint2 p;
                p.x = f2bf(v[0]) | (f2bf(v[1]) << 16);
                p.y = f2bf(v[2]) | (f2bf(v[3]) << 16);
                *(uint2*)&oVT[((size_t)(b * 512 + e)) * 2048 + tok] = p;
            }
        }
        return;
    }

    // LDS-transposed coalesced epilogue (QK bf16 / out-proj fp32)
    const float scale = (MODE == 0 && n0 < 512) ? CEXP : 1.0f;
    float bv[4];
#pragma unroll
    for (int j = 0; j < 4; ++j) bv[j] = bias[n0 + wc + j * 16 + col_l];

    const int erow = tid >> 3, eseg = (tid & 7) * 16;
#pragma unroll
    for (int c = 0; c < 4; ++c) {
        __syncthreads();
        if (wr == (c >> 1) * 64) {
#pragma unroll
            for (int ii = 0; ii < 2; ++ii) {
                const int i = (c & 1) * 2 + ii;
#pragma unroll
                for (int j = 0; j < 4; ++j) {
                    f32x4 v = acc[i][j];
#pragma unroll
                    for (int r = 0; r < 4; ++r)
                        ep[ii * 16 + row_l + r][wc + j * 16 + col_l] = (v[r] + bv[j]) * scale;
                }
            }
        }
        __syncthreads();
        const int grow2 = m0 + c * 32 + erow;
        if (MODE == 0) {
            uint4 o0, o1;
#pragma unroll
            for (int k = 0; k < 4; ++k) {
                uint lo = f2bf(ep[erow][eseg + k * 2])     | (f2bf(ep[erow][eseg + k * 2 + 1]) << 16);
                uint hi = f2bf(ep[erow][eseg + 8 + k * 2]) | (f2bf(ep[erow][eseg + 9 + k * 2]) << 16);
                ((uint*)&o0)[k] = lo; ((uint*)&o1)[k] = hi;
            }
            *(uint4*)&oQK[(size_t)grow2 * 1024 + n0 + eseg]     = o0;
            *(uint4*)&oQK[(size_t)grow2 * 1024 + n0 + eseg + 8] = o1;
        } else {
#pragma unroll
            for (int k = 0; k < 4; ++k) {
                f32x4 v = *(const f32x4*)&ep[erow][eseg + k * 4];
                *(f32x4*)&oC[(size_t)grow2 * 512 + n0 + eseg + k * 4] = v;
            }
        }
    }
}

// ---------------------------------------------------------------------------
// MFMA flash attention, O^T formulation; 64 q-rows per wave (two 32-row
// groups sharing ka/va LDS fragment reads). NEW: softmax row-sum l computed
// on the MFMA pipe via an all-ones A-operand (layout-independent):
//   accL[g] += ones(32x16) * P^T_frag  ->  every reg = l[qrow=lane&31].
// This removes the per-pair masked-add VALU and the final shfl reduction,
// with EXACT numerator/denominator cancellation (same truncated P-tilde).
// Block = 4 waves = 256 q-rows; grid (8, 32, NSLICE). AGPR 96 + VGPR ~110
// -> __launch_bounds__(256,2) (resident waves were <=2/SIMD anyway).
// ---------------------------------------------------------------------------
template<int NSLICE>
__global__ __launch_bounds__(256, 2)
void attn_mfma(const ushort_t* __restrict__ QK, const ushort_t* __restrict__ VT,
               ushort_t* __restrict__ Op, float* __restrict__ Lp,
               ushort_t* __restrict__ AO) {
    __shared__ ushort_t Ks[64][72];       // [krow][d]
    __shared__ ushort_t Vs[64][72];       // [d][krow]  (V^T tile)

    const int tid = threadIdx.x, w = tid >> 6, lane = tid & 63;
    const int qt = blockIdx.x, bh = blockIdx.y, b = bh >> 3, h = bh & 7;
    const int slice = (NSLICE > 1) ? blockIdx.z : 0;
    const int l31 = lane & 31, lhi = lane >> 5;

    // Q B-frags for both q-groups (pre-scaled by CEXP in gemm epilogue)
    const int tok0 = qt * 256 + w * 64 + l31;   // q-group g adds g*32
    bf16x8 qf[2][4];
#pragma unroll
    for (int g = 0; g < 2; ++g)
#pragma unroll
        for (int ks = 0; ks < 4; ++ks)
            qf[g][ks] = *(const bf16x8*)&QK[(size_t)(b * NSEQ + tok0 + g * 32) * 1024
                                            + h * 64 + ks * 16 + lhi * 8];

    f32x16 accO[2][2];   // [g][d-half]
    f32x16 accL[2];      // [g] row-sum accumulator (ones-MFMA)
#pragma unroll
    for (int g = 0; g < 2; ++g) {
#pragma unroll
        for (int i = 0; i < 16; ++i) { accO[g][0][i] = 0.f; accO[g][1][i] = 0.f; accL[g][i] = 0.f; }
    }
    union { uint u[4]; bf16x8 v; } ONE;
    ONE.u[0] = 0x3f803f80u; ONE.u[1] = 0x3f803f80u;
    ONE.u[2] = 0x3f803f80u; ONE.u[3] = 0x3f803f80u;

    // staging: 256 threads, 2 x uint4 per matrix per thread
    const int sr = tid & 63, sc = (tid >> 6) * 16;
    const ushort_t* Kg = QK + (size_t)(b * NSEQ) * 1024 + 512 + h * 64;
    const ushort_t* Vg = VT + ((size_t)(b * 512 + h * 64)) * 2048;

    const int kt0 = slice * (32 / NSLICE), kt1 = kt0 + 32 / NSLICE;
    for (int kt = kt0; kt < kt1; ++kt) {
        const int k0 = kt * 64;
        uint4 kv0 = *(const uint4*)&Kg[(size_t)(k0 + sr) * 1024 + sc];
        uint4 kv1 = *(const uint4*)&Kg[(size_t)(k0 + sr) * 1024 + sc + 8];
        uint4 vv0 = *(const uint4*)&Vg[(size_t)sr * 2048 + k0 + sc];
        uint4 vv1 = *(const uint4*)&Vg[(size_t)sr * 2048 + k0 + sc + 8];
        __syncthreads();                          // prior frag reads done
        *(uint4*)&Ks[sr][sc] = kv0;  *(uint4*)&Ks[sr][sc + 8] = kv1;
        *(uint4*)&Vs[sr][sc] = vv0;  *(uint4*)&Vs[sr][sc + 8] = vv1;
        __syncthreads();                          // tiles visible

#pragma unroll
        for (int ms = 0; ms < 2; ++ms) {   // krow halves 0..31 / 32..63
            bf16x8 ka[4];
#pragma unroll
            for (int ks = 0; ks < 4; ++ks)
                ka[ks] = *(const bf16x8*)&Ks[ms * 32 + l31][ks * 16 + lhi * 8];

            f32x16 st[2];
#pragma unroll
            for (int g = 0; g < 2; ++g)
#pragma unroll
                for (int i = 0; i < 16; ++i) st[g][i] = 0.f;
#pragma unroll
            for (int ks = 0; ks < 4; ++ks) {
                st[0] = __builtin_amdgcn_mfma_f32_32x32x16_bf16(ka[ks], qf[0][ks], st[0], 0, 0, 0);
                st[1] = __builtin_amdgcn_mfma_f32_32x32x16_bf16(ka[ks], qf[1][ks], st[1], 0, 0, 0);
            }

            // P^T = exp2(S^T); truncate to bf16 + pack (no VALU l-sum)
            uint dd[2][8], ee[2][8];
#pragma unroll
            for (int g = 0; g < 2; ++g)
#pragma unroll
                for (int i = 0; i < 8; ++i) {
                    uint ua = __builtin_bit_cast(uint, __builtin_amdgcn_exp2f(st[g][2 * i]));
                    uint ub = __builtin_bit_cast(uint, __builtin_amdgcn_exp2f(st[g][2 * i + 1]));
                    dd[g][i] = (ua >> 16) | (ub & 0xffff0000u);
                }
#pragma unroll
            for (int g = 0; g < 2; ++g)
#pragma unroll
                for (int i = 0; i < 8; ++i)
                    ee[g][i] = (uint)__shfl_xor((int)dd[g][i], 32);

            // PV + ones-l: va shared across q-groups
#pragma unroll
            for (int s = 0; s < 2; ++s) {
                const int step = ms * 2 + s;
                bf16x8 va0 = *(const bf16x8*)&Vs[l31][step * 16 + lhi * 8];
                bf16x8 va1 = *(const bf16x8*)&Vs[32 + l31][step * 16 + lhi * 8];
#pragma unroll
                for (int g = 0; g < 2; ++g) {
                    union { uint u[4]; bf16x8 v; } B;
                    B.u[0] = lhi ? ee[g][4 * s + 2] : dd[g][4 * s + 0];
                    B.u[1] = lhi ? ee[g][4 * s + 3] : dd[g][4 * s + 1];
                    B.u[2] = lhi ? dd[g][4 * s + 2] : ee[g][4 * s + 0];
                    B.u[3] = lhi ? dd[g][4 * s + 3] : ee[g][4 * s + 1];
                    accO[g][0] = __builtin_amdgcn_mfma_f32_32x32x16_bf16(va0, B.v, accO[g][0], 0, 0, 0);
                    accO[g][1] = __builtin_amdgcn_mfma_f32_32x32x16_bf16(va1, B.v, accO[g][1], 0, 0, 0);
                    accL[g]    = __builtin_amdgcn_mfma_f32_32x32x16_bf16(ONE.v, B.v, accL[g], 0, 0, 0);
                }
            }
        }
    }

    // accL[g][r] == l[qrow] for every r (ones rows identical) — no reduction.
    if (NSLICE == 1) {
#pragma unroll
        for (int g = 0; g < 2; ++g) {
            const float inv = 1.0f / accL[g][0];
#pragma unroll
            for (int hf = 0; hf < 2; ++hf)
#pragma unroll
                for (int r = 0; r < 16; ++r) {
                    const int d = (r & 3) + 8 * (r >> 2) + 4 * lhi + 32 * hf;
                    AO[((size_t)(b * NSEQ + tok0 + g * 32)) * 512 + h * 64 + d] =
                        (ushort_t)f2bf(accO[g][hf][r] * inv);
                }
        }
    } else {
        if (lane < 32) {
#pragma unroll
            for (int g = 0; g < 2; ++g)
                Lp[(size_t)slice * 65536 + bh * 2048 + tok0 + g * 32] = accL[g][0];
        }
        ushort_t* Os = Op + (size_t)slice * 4194304;
#pragma unroll
        for (int g = 0; g < 2; ++g)
#pragma unroll
            for (int hf = 0; hf < 2; ++hf)
#pragma unroll
                for (int r = 0; r < 16; ++r) {
                    const int d = (r & 3) + 8 * (r >> 2) + 4 * lhi + 32 * hf;
                    Os[((size_t)(bh * 64 + d)) * 2048 + tok0 + g * 32] =
                        (ushort_t)f2bf(accO[g][hf][r]);
                }
    }
}

// ---------------------------------------------------------------------------
// Combine 2 split-K bf16 partials: AO[tok][e] = sum_s O_s / sum_s l_s.
// ---------------------------------------------------------------------------
__global__ __launch_bounds__(256)
void combine2Tb(const ushort_t* __restrict__ Op, const float* __restrict__ Lp,
                ushort_t* __restrict__ AO) {
    __shared__ float T[64][68];
    const int tid = threadIdx.x;
    const int tc = blockIdx.x, bh = blockIdx.y;
    const int b = bh >> 3, h = bh & 7;
    const int tok0 = tc * 64;

    const int d = tid >> 2, ts = (tid & 3) * 16;
    float acc[16];
#pragma unroll
    for (int i = 0; i < 16; ++i) acc[i] = 0.f;
#pragma unroll
    for (int s = 0; s < 2; ++s) {
        const ushort_t* P = Op + (size_t)s * 4194304
                               + ((size_t)(bh * 64 + d)) * 2048 + tok0 + ts;
#pragma unroll
        for (int k2 = 0; k2 < 2; ++k2) {
            uint4 u = *(const uint4*)(P + 8 * k2);
#pragma unroll
            for (int j = 0; j < 4; ++j) {
                uint uw = ((const uint*)&u)[j];
                acc[k2 * 8 + 2 * j]     += __builtin_bit_cast(float, uw << 16);
                acc[k2 * 8 + 2 * j + 1] += __builtin_bit_cast(float, uw & 0xffff0000u);
            }
        }
    }
#pragma unroll
    for (int k = 0; k < 4; ++k)
        *(f32x4*)&T[d][ts + 4 * k] = *(const f32x4*)&acc[4 * k];
    __syncthreads();

    const int tk = tid >> 2, ds = (tid & 3) * 16;
    const int tok = tok0 + tk;
    const float inv = 1.0f / (Lp[bh * 2048 + tok] + Lp[65536 + bh * 2048 + tok]);
    uint o[8];
#pragma unroll
    for (int k = 0; k < 8; ++k) {
        float a = T[ds + 2 * k][tk] * inv;
        float c = T[ds + 2 * k + 1][tk] * inv;
        o[k] = f2bf(a) | (f2bf(c) << 16);
    }
    ushort_t* dst = AO + ((size_t)(b * NSEQ + tok)) * 512 + h * 64 + ds;
    *(uint4*)dst       = *(const uint4*)&o[0];
    *(uint4*)(dst + 8) = *(const uint4*)&o[4];
}

// ---------------------------------------------------------------------------
extern "C" void kernel_launch(void* const* d_in, const int* in_sizes, int n_in,
                              void* d_out, int out_size, void* d_ws, size_t ws_size,
                              hipStream_t stream) {
    const float* x  = (const float*)d_in[0];
    const float* Wq = (const float*)d_in[1];
    const float* bq = (const float*)d_in[2];
    const float* Wk = (const float*)d_in[3];
    const float* bk = (const float*)d_in[4];
    const float* Wv = (const float*)d_in[5];
    const float* bv = (const float*)d_in[6];
    const float* Wo = (const float*)d_in[7];
    const float* bo = (const float*)d_in[8];

    char* ws = (char*)d_ws;
    ushort_t* Wqkvb = (ushort_t*)(ws + 8388608);             //  1,572,864 B
    ushort_t* Wob   = (ushort_t*)(ws + 9961472);             //    524,288 B
    float*    bqkv  = (float*)   (ws + 10485760);            //      6,144 B
    ushort_t* QKb   = (ushort_t*)(ws + 10491904);            // 16,777,216 B
    ushort_t* VTg   = (ushort_t*)(ws + 27269120);            //  8,388,608 B
    ushort_t* AOb   = (ushort_t*)(ws + 35657728);            //  8,388,608 B
    ushort_t* Opart = (ushort_t*)(ws + 44046336);            // 16,777,216 B (2 slices bf16)
    float*    Lpart = (float*)   (ws);                       //    524,288 B (region unused otherwise)
    const bool split = ws_size >= 78125056;

    prep<<<256, 256, 0, stream>>>(Wq, Wk, Wv, Wo, bq, bk, bv, Wqkvb, bqkv, Wob);
    gemm128<0><<<dim3(64, 12), 256, 0, stream>>>(x, nullptr, Wqkvb, bqkv, QKb, VTg, nullptr);
    if (split) {
        attn_mfma<2><<<dim3(8, 32, 2), 256, 0, stream>>>(QKb, VTg, Opart, Lpart, nullptr);
        combine2Tb<<<dim3(32, 32), 256, 0, stream>>>(Opart, Lpart, AOb);
    } else {
        attn_mfma<1><<<dim3(8, 32, 1), 256, 0, stream>>>(QKb, VTg, nullptr, nullptr, AOb);
    }
    gemm128<1><<<dim3(64, 4), 256, 0, stream>>>(nullptr, AOb, Wob, bo, nullptr, nullptr, (float*)d_out);
}

// Round 9
// 179.509 us; speedup vs baseline: 1.0514x; 1.0514x over previous
//
#include <hip/hip_runtime.h>

typedef float f32x4 __attribute__((ext_vector_type(4)));
typedef float f32x16 __attribute__((ext_vector_type(16)));
typedef short bf16x8 __attribute__((ext_vector_type(8)));
typedef unsigned int uint;
typedef unsigned short ushort_t;

#define EMB    512
#define NSEQ   2048
#define NBATCH 4
#define NHEAD  8
#define MROWS  (NBATCH * NSEQ)   // 8192
#define CEXP   0.06375872f       // log2(e) / sqrt(512)

// round-to-nearest-even fp32 -> bf16 (bit trick)
__device__ __forceinline__ uint f2bf(float x) {
    uint u = __builtin_bit_cast(uint, x);
    return (u + 0x7fffu + ((u >> 16) & 1u)) >> 16;
}

// async global->LDS, 16B per lane; LDS dest = wave-uniform base + lane*16
__device__ __forceinline__ void glds16(const void* g, void* l) {
    __builtin_amdgcn_global_load_lds(
        (const __attribute__((address_space(1))) uint*)g,
        (__attribute__((address_space(3))) uint*)l, 16, 0, 0);
}

// ---------------------------------------------------------------------------
// Prep: x -> bf16; Wq|Wk|Wv -> Wqkvb bf16 [1536][512]; biases concat; Wo -> bf16
// (R7 version restored: glds16 bf16-A beats fp32 register staging — R8 PM.)
// ---------------------------------------------------------------------------
__global__ __launch_bounds__(256)
void prep(const float* __restrict__ x,
          const float* __restrict__ Wq, const float* __restrict__ Wk,
          const float* __restrict__ Wv, const float* __restrict__ Wo,
          const float* __restrict__ bq, const float* __restrict__ bk,
          const float* __restrict__ bv,
          ushort_t* __restrict__ xb, ushort_t* __restrict__ Wqkvb,
          float* __restrict__ bqkv, ushort_t* __restrict__ Wob) {
    int t = blockIdx.x * 256 + threadIdx.x;   // f4-group index, 1048576 total
    {
        float4 v = ((const float4*)x)[t];
        uint2 p;
        p.x = f2bf(v.x) | (f2bf(v.y) << 16);
        p.y = f2bf(v.z) | (f2bf(v.w) << 16);
        ((uint2*)xb)[t] = p;
    }
    if (t < 65536) {   // 512*512/4 groups per weight
        float4 a = ((const float4*)Wq)[t];
        float4 b = ((const float4*)Wk)[t];
        float4 c = ((const float4*)Wv)[t];
        float4 d = ((const float4*)Wo)[t];
        uint2 p;
        p.x = f2bf(a.x) | (f2bf(a.y) << 16); p.y = f2bf(a.z) | (f2bf(a.w) << 16);
        ((uint2*)Wqkvb)[t] = p;
        p.x = f2bf(b.x) | (f2bf(b.y) << 16); p.y = f2bf(b.z) | (f2bf(b.w) << 16);
        ((uint2*)Wqkvb)[t + 65536] = p;
        p.x = f2bf(c.x) | (f2bf(c.y) << 16); p.y = f2bf(c.z) | (f2bf(c.w) << 16);
        ((uint2*)Wqkvb)[t + 131072] = p;
        p.x = f2bf(d.x) | (f2bf(d.y) << 16); p.y = f2bf(d.z) | (f2bf(d.w) << 16);
        ((uint2*)Wob)[t] = p;
    }
    if (t < 512) {
        bqkv[t] = bq[t]; bqkv[512 + t] = bk[t]; bqkv[1024 + t] = bv[t];
    }
}

// ---------------------------------------------------------------------------
// GEMM C[8192 x N] = A[8192x512]bf16 * BT[Nx512]bf16 + bias, 128x128 tile,
// BK=64 via DUAL unpadded [128][32] sub-tiles: 8 glds16/wave then ONE
// barrier-pair per 64-k, 32 MFMA between barriers (halves barrier drains vs
// BK=32; keeps m97's conflict-free layout — padding would break glds16's
// wave-uniform LDS dest). 8 kt iterations. 4 waves, 16x16x32 mfma, 4x4/wave.
// MODE 0: QKV (N=1536): n0<1024 -> LDS-transposed coalesced bf16 stores
//         (Q cols pre-scaled by CEXP); n0>=1024 -> transposed stores to VTg.
// MODE 1: out proj (N=512): LDS-transposed coalesced fp32 stores + bias.
// ---------------------------------------------------------------------------
template<int MODE>
__global__ __launch_bounds__(256)
void gemm128(const ushort_t* __restrict__ A, const ushort_t* __restrict__ BT,
             const float* __restrict__ bias, ushort_t* __restrict__ oQK,
             ushort_t* __restrict__ oVT, float* __restrict__ oC) {
    __shared__ ushort_t As[2][128][32];   // 16 KB, unpadded sub-tiles
    __shared__ ushort_t Bs[2][128][32];
    __shared__ float ep[32][132];         // epilogue transpose buffer (16.9 KB)
    const int tid = threadIdx.x, wave = tid >> 6, lane = tid & 63;
    const int m0 = blockIdx.x * 128, n0 = blockIdx.y * 128;
    const int wr = (wave & 1) * 64, wc = (wave >> 1) * 64;

    f32x4 acc[4][4];
#pragma unroll
    for (int i = 0; i < 4; ++i)
#pragma unroll
        for (int j = 0; j < 4; ++j) acc[i][j] = (f32x4){0.f, 0.f, 0.f, 0.f};

    // per-lane global source: row = wave*16 + lane/4, col-seg = (lane&3)*16B
    const int grow = wave * 16 + (lane >> 2);
    const int gcol = (lane & 3) * 8;
    const ushort_t* Ag = A  + (size_t)(m0 + grow) * 512 + gcol;
    const ushort_t* Bg = BT + (size_t)(n0 + grow) * 512 + gcol;
    const int fr = lane & 15, fc = (lane >> 4) * 8;

    for (int kt = 0; kt < 8; ++kt) {
        __syncthreads();   // prior frag reads done before overwrite
#pragma unroll
        for (int t = 0; t < 2; ++t) {
            glds16(Ag + kt * 64 + t * 32,            &As[t][wave * 16][0]);
            glds16(Ag + kt * 64 + t * 32 + 64 * 512, &As[t][64 + wave * 16][0]);
            glds16(Bg + kt * 64 + t * 32,            &Bs[t][wave * 16][0]);
            glds16(Bg + kt * 64 + t * 32 + 64 * 512, &Bs[t][64 + wave * 16][0]);
        }
        __syncthreads();   // vmcnt(0) drained -> both sub-tiles visible
#pragma unroll
        for (int t = 0; t < 2; ++t) {
            bf16x8 af[4], bf[4];
#pragma unroll
            for (int i = 0; i < 4; ++i) af[i] = *(const bf16x8*)&As[t][wr + i * 16 + fr][fc];
#pragma unroll
            for (int j = 0; j < 4; ++j) bf[j] = *(const bf16x8*)&Bs[t][wc + j * 16 + fr][fc];
#pragma unroll
            for (int i = 0; i < 4; ++i)
#pragma unroll
                for (int j = 0; j < 4; ++j)
                    acc[i][j] = __builtin_amdgcn_mfma_f32_16x16x32_bf16(af[i], bf[j], acc[i][j], 0, 0, 0);
        }
    }

    const int col_l = lane & 15, row_l = (lane >> 4) * 4;

    if (MODE == 0 && n0 >= 1024) {
        // V part: direct transposed packed stores
#pragma unroll
        for (int j = 0; j < 4; ++j) {
            const int col = n0 + wc + j * 16 + col_l;
            const float bv = bias[col];
#pragma unroll
            for (int i = 0; i < 4; ++i) {
                const int row = m0 + wr + i * 16 + row_l;
                f32x4 v = acc[i][j];
                v += (f32x4){bv, bv, bv, bv};
                const int e = col - 1024;
                const int b = row >> 11, tok = row & 2047;
                uint2 p;
                p.x = f2bf(v[0]) | (f2bf(v[1]) << 16);
                p.y = f2bf(v[2]) | (f2bf(v[3]) << 16);
                *(uint2*)&oVT[((size_t)(b * 512 + e)) * 2048 + tok] = p;
            }
        }
        return;
    }

    // LDS-transposed coalesced epilogue (QK bf16 / out-proj fp32)
    const float scale = (MODE == 0 && n0 < 512) ? CEXP : 1.0f;
    float bv[4];
#pragma unroll
    for (int j = 0; j < 4; ++j) bv[j] = bias[n0 + wc + j * 16 + col_l];

    const int erow = tid >> 3, eseg = (tid & 7) * 16;
#pragma unroll
    for (int c = 0; c < 4; ++c) {
        __syncthreads();
        if (wr == (c >> 1) * 64) {
#pragma unroll
            for (int ii = 0; ii < 2; ++ii) {
                const int i = (c & 1) * 2 + ii;
#pragma unroll
                for (int j = 0; j < 4; ++j) {
                    f32x4 v = acc[i][j];
#pragma unroll
                    for (int r = 0; r < 4; ++r)
                        ep[ii * 16 + row_l + r][wc + j * 16 + col_l] = (v[r] + bv[j]) * scale;
                }
            }
        }
        __syncthreads();
        const int grow2 = m0 + c * 32 + erow;
        if (MODE == 0) {
            uint4 o0, o1;
#pragma unroll
            for (int k = 0; k < 4; ++k) {
                uint lo = f2bf(ep[erow][eseg + k * 2])     | (f2bf(ep[erow][eseg + k * 2 + 1]) << 16);
                uint hi = f2bf(ep[erow][eseg + 8 + k * 2]) | (f2bf(ep[erow][eseg + 9 + k * 2]) << 16);
                ((uint*)&o0)[k] = lo; ((uint*)&o1)[k] = hi;
            }
            *(uint4*)&oQK[(size_t)grow2 * 1024 + n0 + eseg]     = o0;
            *(uint4*)&oQK[(size_t)grow2 * 1024 + n0 + eseg + 8] = o1;
        } else {
#pragma unroll
            for (int k = 0; k < 4; ++k) {
                f32x4 v = *(const f32x4*)&ep[erow][eseg + k * 4];
                *(f32x4*)&oC[(size_t)grow2 * 512 + n0 + eseg + k * 4] = v;
            }
        }
    }
}

// ---------------------------------------------------------------------------
// MFMA flash attention, O^T formulation; 64 q-rows per wave (two 32-row
// groups sharing ka/va LDS fragment reads). Softmax row-sum l on the MFMA
// pipe via all-ones A-operand (layout-independent); exact num/denom
// cancellation (same truncated P-tilde). Unchanged from round 8 (53.2 µs,
// MfmaUtil 32%, VGPR 124, no spill).
// ---------------------------------------------------------------------------
template<int NSLICE>
__global__ __launch_bounds__(256, 2)
void attn_mfma(const ushort_t* __restrict__ QK, const ushort_t* __restrict__ VT,
               ushort_t* __restrict__ Op, float* __restrict__ Lp,
               ushort_t* __restrict__ AO) {
    __shared__ ushort_t Ks[64][72];       // [krow][d]
    __shared__ ushort_t Vs[64][72];       // [d][krow]  (V^T tile)

    const int tid = threadIdx.x, w = tid >> 6, lane = tid & 63;
    const int qt = blockIdx.x, bh = blockIdx.y, b = bh >> 3, h = bh & 7;
    const int slice = (NSLICE > 1) ? blockIdx.z : 0;
    const int l31 = lane & 31, lhi = lane >> 5;

    const int tok0 = qt * 256 + w * 64 + l31;   // q-group g adds g*32
    bf16x8 qf[2][4];
#pragma unroll
    for (int g = 0; g < 2; ++g)
#pragma unroll
        for (int ks = 0; ks < 4; ++ks)
            qf[g][ks] = *(const bf16x8*)&QK[(size_t)(b * NSEQ + tok0 + g * 32) * 1024
                                            + h * 64 + ks * 16 + lhi * 8];

    f32x16 accO[2][2];   // [g][d-half]
    f32x16 accL[2];      // [g] row-sum accumulator (ones-MFMA)
#pragma unroll
    for (int g = 0; g < 2; ++g) {
#pragma unroll
        for (int i = 0; i < 16; ++i) { accO[g][0][i] = 0.f; accO[g][1][i] = 0.f; accL[g][i] = 0.f; }
    }
    union { uint u[4]; bf16x8 v; } ONE;
    ONE.u[0] = 0x3f803f80u; ONE.u[1] = 0x3f803f80u;
    ONE.u[2] = 0x3f803f80u; ONE.u[3] = 0x3f803f80u;

    const int sr = tid & 63, sc = (tid >> 6) * 16;
    const ushort_t* Kg = QK + (size_t)(b * NSEQ) * 1024 + 512 + h * 64;
    const ushort_t* Vg = VT + ((size_t)(b * 512 + h * 64)) * 2048;

    const int kt0 = slice * (32 / NSLICE), kt1 = kt0 + 32 / NSLICE;
    for (int kt = kt0; kt < kt1; ++kt) {
        const int k0 = kt * 64;
        uint4 kv0 = *(const uint4*)&Kg[(size_t)(k0 + sr) * 1024 + sc];
        uint4 kv1 = *(const uint4*)&Kg[(size_t)(k0 + sr) * 1024 + sc + 8];
        uint4 vv0 = *(const uint4*)&Vg[(size_t)sr * 2048 + k0 + sc];
        uint4 vv1 = *(const uint4*)&Vg[(size_t)sr * 2048 + k0 + sc + 8];
        __syncthreads();                          // prior frag reads done
        *(uint4*)&Ks[sr][sc] = kv0;  *(uint4*)&Ks[sr][sc + 8] = kv1;
        *(uint4*)&Vs[sr][sc] = vv0;  *(uint4*)&Vs[sr][sc + 8] = vv1;
        __syncthreads();                          // tiles visible

#pragma unroll
        for (int ms = 0; ms < 2; ++ms) {   // krow halves 0..31 / 32..63
            bf16x8 ka[4];
#pragma unroll
            for (int ks = 0; ks < 4; ++ks)
                ka[ks] = *(const bf16x8*)&Ks[ms * 32 + l31][ks * 16 + lhi * 8];

            f32x16 st[2];
#pragma unroll
            for (int g = 0; g < 2; ++g)
#pragma unroll
                for (int i = 0; i < 16; ++i) st[g][i] = 0.f;
#pragma unroll
            for (int ks = 0; ks < 4; ++ks) {
                st[0] = __builtin_amdgcn_mfma_f32_32x32x16_bf16(ka[ks], qf[0][ks], st[0], 0, 0, 0);
                st[1] = __builtin_amdgcn_mfma_f32_32x32x16_bf16(ka[ks], qf[1][ks], st[1], 0, 0, 0);
            }

            uint dd[2][8], ee[2][8];
#pragma unroll
            for (int g = 0; g < 2; ++g)
#pragma unroll
                for (int i = 0; i < 8; ++i) {
                    uint ua = __builtin_bit_cast(uint, __builtin_amdgcn_exp2f(st[g][2 * i]));
                    uint ub = __builtin_bit_cast(uint, __builtin_amdgcn_exp2f(st[g][2 * i + 1]));
                    dd[g][i] = (ua >> 16) | (ub & 0xffff0000u);
                }
#pragma unroll
            for (int g = 0; g < 2; ++g)
#pragma unroll
                for (int i = 0; i < 8; ++i)
                    ee[g][i] = (uint)__shfl_xor((int)dd[g][i], 32);

#pragma unroll
            for (int s = 0; s < 2; ++s) {
                const int step = ms * 2 + s;
                bf16x8 va0 = *(const bf16x8*)&Vs[l31][step * 16 + lhi * 8];
                bf16x8 va1 = *(const bf16x8*)&Vs[32 + l31][step * 16 + lhi * 8];
#pragma unroll
                for (int g = 0; g < 2; ++g) {
                    union { uint u[4]; bf16x8 v; } B;
                    B.u[0] = lhi ? ee[g][4 * s + 2] : dd[g][4 * s + 0];
                    B.u[1] = lhi ? ee[g][4 * s + 3] : dd[g][4 * s + 1];
                    B.u[2] = lhi ? dd[g][4 * s + 2] : ee[g][4 * s + 0];
                    B.u[3] = lhi ? dd[g][4 * s + 3] : ee[g][4 * s + 1];
                    accO[g][0] = __builtin_amdgcn_mfma_f32_32x32x16_bf16(va0, B.v, accO[g][0], 0, 0, 0);
                    accO[g][1] = __builtin_amdgcn_mfma_f32_32x32x16_bf16(va1, B.v, accO[g][1], 0, 0, 0);
                    accL[g]    = __builtin_amdgcn_mfma_f32_32x32x16_bf16(ONE.v, B.v, accL[g], 0, 0, 0);
                }
            }
        }
    }

    // accL[g][r] == l[qrow] for every r — no reduction needed.
    if (NSLICE == 1) {
#pragma unroll
        for (int g = 0; g < 2; ++g) {
            const float inv = 1.0f / accL[g][0];
#pragma unroll
            for (int hf = 0; hf < 2; ++hf)
#pragma unroll
                for (int r = 0; r < 16; ++r) {
                    const int d = (r & 3) + 8 * (r >> 2) + 4 * lhi + 32 * hf;
                    AO[((size_t)(b * NSEQ + tok0 + g * 32)) * 512 + h * 64 + d] =
                        (ushort_t)f2bf(accO[g][hf][r] * inv);
                }
        }
    } else {
        if (lane < 32) {
#pragma unroll
            for (int g = 0; g < 2; ++g)
                Lp[(size_t)slice * 65536 + bh * 2048 + tok0 + g * 32] = accL[g][0];
        }
        ushort_t* Os = Op + (size_t)slice * 4194304;
#pragma unroll
        for (int g = 0; g < 2; ++g)
#pragma unroll
            for (int hf = 0; hf < 2; ++hf)
#pragma unroll
                for (int r = 0; r < 16; ++r) {
                    const int d = (r & 3) + 8 * (r >> 2) + 4 * lhi + 32 * hf;
                    Os[((size_t)(bh * 64 + d)) * 2048 + tok0 + g * 32] =
                        (ushort_t)f2bf(accO[g][hf][r]);
                }
    }
}

// ---------------------------------------------------------------------------
// Combine 2 split-K bf16 partials: AO[tok][e] = sum_s O_s / sum_s l_s.
// ---------------------------------------------------------------------------
__global__ __launch_bounds__(256)
void combine2Tb(const ushort_t* __restrict__ Op, const float* __restrict__ Lp,
                ushort_t* __restrict__ AO) {
    __shared__ float T[64][68];
    const int tid = threadIdx.x;
    const int tc = blockIdx.x, bh = blockIdx.y;
    const int b = bh >> 3, h = bh & 7;
    const int tok0 = tc * 64;

    const int d = tid >> 2, ts = (tid & 3) * 16;
    float acc[16];
#pragma unroll
    for (int i = 0; i < 16; ++i) acc[i] = 0.f;
#pragma unroll
    for (int s = 0; s < 2; ++s) {
        const ushort_t* P = Op + (size_t)s * 4194304
                               + ((size_t)(bh * 64 + d)) * 2048 + tok0 + ts;
#pragma unroll
        for (int k2 = 0; k2 < 2; ++k2) {
            uint4 u = *(const uint4*)(P + 8 * k2);
#pragma unroll
            for (int j = 0; j < 4; ++j) {
                uint uw = ((const uint*)&u)[j];
                acc[k2 * 8 + 2 * j]     += __builtin_bit_cast(float, uw << 16);
                acc[k2 * 8 + 2 * j + 1] += __builtin_bit_cast(float, uw & 0xffff0000u);
            }
        }
    }
#pragma unroll
    for (int k = 0; k < 4; ++k)
        *(f32x4*)&T[d][ts + 4 * k] = *(const f32x4*)&acc[4 * k];
    __syncthreads();

    const int tk = tid >> 2, ds = (tid & 3) * 16;
    const int tok = tok0 + tk;
    const float inv = 1.0f / (Lp[bh * 2048 + tok] + Lp[65536 + bh * 2048 + tok]);
    uint o[8];
#pragma unroll
    for (int k = 0; k < 8; ++k) {
        float a = T[ds + 2 * k][tk] * inv;
        float c = T[ds + 2 * k + 1][tk] * inv;
        o[k] = f2bf(a) | (f2bf(c) << 16);
    }
    ushort_t* dst = AO + ((size_t)(b * NSEQ + tok)) * 512 + h * 64 + ds;
    *(uint4*)dst       = *(const uint4*)&o[0];
    *(uint4*)(dst + 8) = *(const uint4*)&o[4];
}

// ---------------------------------------------------------------------------
extern "C" void kernel_launch(void* const* d_in, const int* in_sizes, int n_in,
                              void* d_out, int out_size, void* d_ws, size_t ws_size,
                              hipStream_t stream) {
    const float* x  = (const float*)d_in[0];
    const float* Wq = (const float*)d_in[1];
    const float* bq = (const float*)d_in[2];
    const float* Wk = (const float*)d_in[3];
    const float* bk = (const float*)d_in[4];
    const float* Wv = (const float*)d_in[5];
    const float* bv = (const float*)d_in[6];
    const float* Wo = (const float*)d_in[7];
    const float* bo = (const float*)d_in[8];

    char* ws = (char*)d_ws;
    ushort_t* xb    = (ushort_t*)(ws);                       //  8,388,608 B
    ushort_t* Wqkvb = (ushort_t*)(ws + 8388608);             //  1,572,864 B
    ushort_t* Wob   = (ushort_t*)(ws + 9961472);             //    524,288 B
    float*    bqkv  = (float*)   (ws + 10485760);            //      6,144 B
    ushort_t* QKb   = (ushort_t*)(ws + 10491904);            // 16,777,216 B
    ushort_t* VTg   = (ushort_t*)(ws + 27269120);            //  8,388,608 B
    ushort_t* AOb   = (ushort_t*)(ws + 35657728);            //  8,388,608 B
    ushort_t* Opart = (ushort_t*)(ws + 44046336);            // 16,777,216 B (2 slices bf16)
    float*    Lpart = (float*)   (ws);                       //    524,288 B overlay on xb
                                                             //  (xb dead after gemm<0>)
    const bool split = ws_size >= 78125056;

    prep<<<4096, 256, 0, stream>>>(x, Wq, Wk, Wv, Wo, bq, bk, bv,
                                   xb, Wqkvb, bqkv, Wob);
    gemm128<0><<<dim3(64, 12), 256, 0, stream>>>(xb, Wqkvb, bqkv, QKb, VTg, nullptr);
    if (split) {
        attn_mfma<2><<<dim3(8, 32, 2), 256, 0, stream>>>(QKb, VTg, Opart, Lpart, nullptr);
        combine2Tb<<<dim3(32, 32), 256, 0, stream>>>(Opart, Lpart, AOb);
    } else {
        attn_mfma<1><<<dim3(8, 32, 1), 256, 0, stream>>>(QKb, VTg, nullptr, nullptr, AOb);
    }
    gemm128<1><<<dim3(64, 4), 256, 0, stream>>>(AOb, Wob, bo, nullptr, nullptr, (float*)d_out);
}